// Round 1
// baseline (109.264 us; speedup 1.0000x reference)
//
#include <hip/hip_runtime.h>
#include <hip/hip_bf16.h>

// Shapes
#define B_SZ   256
#define C_SZ   1024
#define HW     49
#define KDIM   50176        // C*H*W
#define DHID   768
#define NCLS   5

typedef __bf16 bf16x8 __attribute__((ext_vector_type(8)));
typedef __bf16 bf16x4 __attribute__((ext_vector_type(4)));
typedef float  f32x4  __attribute__((ext_vector_type(4)));

#define GLOAD_LDS16(gsrc, ldst) \
  __builtin_amdgcn_global_load_lds((__attribute__((address_space(1))) void*)(gsrc), \
                                   (__attribute__((address_space(3))) void*)(ldst), 16, 0, 0)

// ---------------------------------------------------------------------------
// Kernel A: per-(b,c) spatial max, pcam = feat*max -> bf16 (ws), copy feat -> out
// 32 rows of 49 per block (1568 floats), staged in LDS.
// ---------------------------------------------------------------------------
__global__ __launch_bounds__(256) void pcam_kernel(const float* __restrict__ feat,
                                                   float* __restrict__ feat_out,
                                                   __bf16* __restrict__ pcam) {
  __shared__ float sv[1568];
  __shared__ float smax[32];
  const int tid = threadIdx.x;
  const size_t base = (size_t)blockIdx.x * 1568;

  const float4* src4 = (const float4*)(feat + base);
  float4* dst4 = (float4*)(feat_out + base);
  #pragma unroll
  for (int i = 0; i < 2; ++i) {
    int idx = tid + i * 256;
    if (idx < 392) {
      float4 v = src4[idx];
      dst4[idx] = v;                 // feature pass-through output
      ((float4*)sv)[idx] = v;
    }
  }
  __syncthreads();

  // per-row max: 8 lanes per row (consecutive lanes, same wave)
  {
    const int r = tid >> 3, p = tid & 7;
    float mx = -INFINITY;
    for (int i = p; i < HW; i += 8) mx = fmaxf(mx, sv[r * HW + i]);
    #pragma unroll
    for (int off = 1; off < 8; off <<= 1) mx = fmaxf(mx, __shfl_xor(mx, off));
    if (p == 0) smax[r] = mx;
  }
  __syncthreads();

  for (int i = tid; i < 1568; i += 256) {
    int r = (i * 1338) >> 16;        // i/49 exact for i<1568
    float v = sv[i] * smax[r];
    pcam[base + i] = (__bf16)v;      // RNE
  }
}

// ---------------------------------------------------------------------------
// Kernel B: h_acc += pcam[256xK] @ W1[768xK]^T, bf16 MFMA, split-K with atomics.
// M-tile 256 (full M, W1 streamed exactly once), N-tile 128, BK 64, 8 waves.
// A staged via global_load_lds (swizzled global addresses -> linear LDS);
// B reg-staged fp32->bf16 with swizzled ds_write. XOR swizzle: 16B block
// index ^= (row&7) -> ds_read_b128 fragment reads are 2-way max.
// ---------------------------------------------------------------------------
#define BM 256
#define BN 128
#define BK 64
#define NT 6
#define KSPLIT 42
#define KSTEPS 784          // KDIM/BK

__global__ __launch_bounds__(512, 2) void gemm1_kernel(const __bf16* __restrict__ pcam,
                                                       const float* __restrict__ W1,
                                                       float* __restrict__ h_acc) {
  __shared__ __bf16 Asm[BM * BK];   // 32KB, physically swizzled
  __shared__ __bf16 Bsm[BN * BK];   // 16KB, physically swizzled

  const int tid  = threadIdx.x;
  const int lane = tid & 63;
  const int w    = tid >> 6;        // 0..7
  const int wm   = w >> 1;          // 0..3 (64-row slab)
  const int wn   = w & 1;           // 0..1 (64-col slab)
  const int n0   = blockIdx.x * BN;
  const int ks   = blockIdx.y;
  const int s0   = (ks * KSTEPS) / KSPLIT;
  const int s1   = ((ks + 1) * KSTEPS) / KSPLIT;

  f32x4 acc[4][4];
  #pragma unroll
  for (int i = 0; i < 4; ++i)
    #pragma unroll
    for (int j = 0; j < 4; ++j) acc[i][j] = f32x4{0.f, 0.f, 0.f, 0.f};

  for (int s = s0; s < s1; ++s) {
    const int k0 = s * BK;

    // ---- stage A: 2048 x 16B blocks, 4 iters, global addr pre-swizzled
    #pragma unroll
    for (int it = 0; it < 4; ++it) {
      const int q   = it * 512 + tid;     // 16B block id
      const int m   = q >> 3;
      const int kbp = q & 7;              // physical block in row
      const int kbl = kbp ^ (m & 7);      // logical block (XOR swizzle)
      const __bf16* src = pcam + (size_t)m * KDIM + k0 + kbl * 8;
      __bf16* ldsb = Asm + (size_t)(it * 512 + w * 64) * 8;  // wave-uniform
      GLOAD_LDS16(src, ldsb);
    }

    // ---- stage B: fp32 W1 -> bf16, swizzled ds_write (8B per thread per iter)
    #pragma unroll
    for (int it = 0; it < 4; ++it) {
      const int f  = it * 512 + tid;      // float4 id
      const int n  = f >> 4;              // 0..127
      const int kq = f & 15;              // float4 within row
      const float4 v = *(const float4*)(W1 + (size_t)(n0 + n) * KDIM + k0 + kq * 4);
      bf16x4 bv;
      bv[0] = (__bf16)v.x; bv[1] = (__bf16)v.y; bv[2] = (__bf16)v.z; bv[3] = (__bf16)v.w;
      const int kb   = kq >> 1;
      const int phys = n * 128 + (((kb ^ (n & 7)) << 4) | ((kq & 1) << 3)); // bytes
      *(bf16x4*)((char*)Bsm + phys) = bv;
    }
    __syncthreads();

    // ---- compute: 32 MFMAs (4m x 4n x 2ksub)
    #pragma unroll
    for (int ksub = 0; ksub < 2; ++ksub) {
      bf16x8 af[4], bfr[4];
      const int kb = ksub * 4 + (lane >> 4);   // logical 16B block 0..7
      #pragma unroll
      for (int i = 0; i < 4; ++i) {
        const int m = wm * 64 + i * 16 + (lane & 15);
        af[i] = *(const bf16x8*)((const char*)Asm + m * 128 + ((kb ^ (m & 7)) << 4));
      }
      #pragma unroll
      for (int j = 0; j < 4; ++j) {
        const int n = wn * 64 + j * 16 + (lane & 15);
        bfr[j] = *(const bf16x8*)((const char*)Bsm + n * 128 + ((kb ^ (n & 7)) << 4));
      }
      #pragma unroll
      for (int i = 0; i < 4; ++i)
        #pragma unroll
        for (int j = 0; j < 4; ++j)
          acc[i][j] = __builtin_amdgcn_mfma_f32_16x16x32_bf16(af[i], bfr[j], acc[i][j], 0, 0, 0);
    }
    __syncthreads();
  }

  // ---- epilogue: split-K accumulate (C/D layout: col=lane&15, row=(lane>>4)*4+r)
  #pragma unroll
  for (int i = 0; i < 4; ++i) {
    const int mb = wm * 64 + i * 16 + (lane >> 4) * 4;
    #pragma unroll
    for (int j = 0; j < 4; ++j) {
      const int n = n0 + wn * 64 + j * 16 + (lane & 15);
      #pragma unroll
      for (int r = 0; r < 4; ++r)
        unsafeAtomicAdd(&h_acc[(size_t)(mb + r) * DHID + n], acc[i][j][r]);
    }
  }
}

// ---------------------------------------------------------------------------
// Kernel C: h = relu(h_acc + b1); logits = h @ W2^T + b2. One wave per batch row.
// ---------------------------------------------------------------------------
__global__ __launch_bounds__(64) void head_kernel(const float* __restrict__ h_acc,
                                                  const float* __restrict__ b1,
                                                  const float* __restrict__ W2,
                                                  const float* __restrict__ b2,
                                                  float* __restrict__ logits) {
  const int m = blockIdx.x;
  const int lane = threadIdx.x;
  float hv[12];
  #pragma unroll
  for (int j = 0; j < 12; ++j) {
    float v = h_acc[(size_t)m * DHID + j * 64 + lane] + b1[j * 64 + lane];
    hv[j] = v > 0.f ? v : 0.f;
  }
  #pragma unroll
  for (int c = 0; c < NCLS; ++c) {
    float s = 0.f;
    #pragma unroll
    for (int j = 0; j < 12; ++j) s += hv[j] * W2[c * DHID + j * 64 + lane];
    #pragma unroll
    for (int off = 32; off > 0; off >>= 1) s += __shfl_xor(s, off);
    if (lane == 0) logits[m * NCLS + c] = s + b2[c];
  }
}

// ---------------------------------------------------------------------------
extern "C" void kernel_launch(void* const* d_in, const int* in_sizes, int n_in,
                              void* d_out, int out_size, void* d_ws, size_t ws_size,
                              hipStream_t stream) {
  const float* feat = (const float*)d_in[0];
  const float* W1   = (const float*)d_in[1];
  const float* b1   = (const float*)d_in[2];
  const float* W2   = (const float*)d_in[3];
  const float* b2   = (const float*)d_in[4];

  float* logits   = (float*)d_out;                    // [256,5]
  float* feat_out = (float*)d_out + (size_t)B_SZ * NCLS;  // [256,1024,7,7]

  __bf16* pcam  = (__bf16*)d_ws;                           // 256*50176*2 = 25,690,112 B
  float*  h_acc = (float*)((char*)d_ws + (size_t)B_SZ * KDIM * 2); // 256*768*4 B

  hipMemsetAsync(h_acc, 0, (size_t)B_SZ * DHID * sizeof(float), stream);
  pcam_kernel<<<(B_SZ * C_SZ) / 32, 256, 0, stream>>>(feat, feat_out, pcam);
  gemm1_kernel<<<dim3(NT, KSPLIT), 512, 0, stream>>>(pcam, W1, h_acc);
  head_kernel<<<B_SZ, 64, 0, stream>>>(h_acc, b1, W2, b2, logits);
}